// Round 10
// baseline (816.697 us; speedup 1.0000x reference)
//
#include <hip/hip_runtime.h>
#include <hip/hip_bf16.h>
#include <stdint.h>

#define DEV __device__ __forceinline__

typedef __bf16 bf16x8 __attribute__((ext_vector_type(8)));
typedef float f32x4 __attribute__((ext_vector_type(4)));
typedef unsigned short us8 __attribute__((ext_vector_type(8)));
typedef int8_t i8x8 __attribute__((ext_vector_type(8)));

DEV unsigned short f2us(float f) {
  __hip_bfloat16 h = __float2bfloat16(f);
  unsigned short u;
  __builtin_memcpy(&u, &h, 2);
  return u;
}

DEV double wave_reduce_d(double v) {
#pragma unroll
  for (int off = 32; off > 0; off >>= 1) v += __shfl_down(v, off);
  return v;
}

DEV double dbl_block_reduce(double v, double* lds) {
  v = wave_reduce_d(v);
  int lane = threadIdx.x & 63, w = threadIdx.x >> 6;
  if (lane == 0) lds[w] = v;
  __syncthreads();
  double r = 0.0;
  if (threadIdx.x == 0) r = lds[0] + lds[1] + lds[2] + lds[3];
  __syncthreads();
  return r;
}

// ---------------- ternarize: fp64 stats, 4x-unrolled float4 sweeps ----------------
// grid 2048 x 6: 32 waves/CU (R9's 1024 gave 49% occupancy -> latency-bound at 1.2 TB/s)
struct TDesc { const float* w; int n; };
struct TDescs { TDesc d[6]; };

DEV double abs4d(float4 v) {
  return fabs((double)v.x) + fabs((double)v.y) + fabs((double)v.z) + fabs((double)v.w);
}

__global__ __launch_bounds__(256) void tern_abs_all(TDescs td, double* __restrict__ st) {
  __shared__ double lds[4];
  const int t = blockIdx.y;
  const float4* w4 = (const float4*)td.d[t].w;
  const int n4 = td.d[t].n >> 2;
  const int S = gridDim.x * 256;
  int i = blockIdx.x * 256 + threadIdx.x;
  double s0 = 0.0, s1 = 0.0, s2 = 0.0, s3 = 0.0;
  for (; i + 3 * S < n4; i += 4 * S) {
    float4 v0 = w4[i];
    float4 v1 = w4[i + S];
    float4 v2 = w4[i + 2 * S];
    float4 v3 = w4[i + 3 * S];
    s0 += abs4d(v0);
    s1 += abs4d(v1);
    s2 += abs4d(v2);
    s3 += abs4d(v3);
  }
  for (; i < n4; i += S) s0 += abs4d(w4[i]);
  double s = (s0 + s1) + (s2 + s3);
  s = dbl_block_reduce(s, lds);
  if (threadIdx.x == 0 && s != 0.0) atomicAdd(st + t * 4, s);
}

struct MDesc { const float* w; int8_t* out; int n; };
struct MDescs { MDesc d[6]; };

DEV int proc4(float4 v, double delta, double& ms, double& cnt) {
  float e[4] = {v.x, v.y, v.z, v.w};
  char pk[4];
#pragma unroll
  for (int j = 0; j < 4; ++j) {
    double d = (double)e[j];
    double a = fabs(d);
    if (a > delta) { ms += a; cnt += 1.0; }
    pk[j] = (char)((d > delta) ? 1 : ((d < -delta) ? -1 : 0));
  }
  int w32;
  __builtin_memcpy(&w32, pk, 4);
  return w32;
}

__global__ __launch_bounds__(256) void tern_masked_code_all(MDescs td, double* __restrict__ st) {
  __shared__ double lds[4];
  const int t = blockIdx.y;
  const float4* w4 = (const float4*)td.d[t].w;
  int8_t* out = td.d[t].out;
  const int n4 = td.d[t].n >> 2;
  const double delta = 0.7 * st[t * 4] / (double)td.d[t].n;
  const int S = gridDim.x * 256;
  int i = blockIdx.x * 256 + threadIdx.x;
  double m0 = 0.0, m1 = 0.0, m2 = 0.0, m3 = 0.0;
  double c0 = 0.0, c1x = 0.0, c2x = 0.0, c3 = 0.0;
  for (; i + 3 * S < n4; i += 4 * S) {
    float4 v0 = w4[i];
    float4 v1 = w4[i + S];
    float4 v2 = w4[i + 2 * S];
    float4 v3 = w4[i + 3 * S];
    int p0 = proc4(v0, delta, m0, c0);
    int p1 = proc4(v1, delta, m1, c1x);
    int p2 = proc4(v2, delta, m2, c2x);
    int p3 = proc4(v3, delta, m3, c3);
    if (out) {
      *(int*)(out + ((size_t)i << 2)) = p0;
      *(int*)(out + ((size_t)(i + S) << 2)) = p1;
      *(int*)(out + ((size_t)(i + 2 * S) << 2)) = p2;
      *(int*)(out + ((size_t)(i + 3 * S) << 2)) = p3;
    }
  }
  for (; i < n4; i += S) {
    int p = proc4(w4[i], delta, m0, c0);
    if (out) *(int*)(out + ((size_t)i << 2)) = p;
  }
  double ms = (m0 + m1) + (m2 + m3);
  double cnt = (c0 + c1x) + (c2x + c3);
  ms = dbl_block_reduce(ms, lds);
  cnt = dbl_block_reduce(cnt, lds);
  if (threadIdx.x == 0 && cnt != 0.0) {
    atomicAdd(st + t * 4 + 1, ms);
    atomicAdd(st + t * 4 + 2, cnt);
  }
}

DEV float tern_alpha_d(const double* st, double n) {
  double cnt = st[2];
  return (float)(cnt > 0.0 ? st[1] / fmax(cnt, 1.0) : st[0] / n);
}
DEV double tern_alpha_dd(const double* st, double n) {
  double cnt = st[2];
  return cnt > 0.0 ? st[1] / fmax(cnt, 1.0) : st[0] / n;
}

// conv2-4 weights -> bf16 codes {-1,0,+1}, layout [cout][k=tap*CIN+ci]
__global__ __launch_bounds__(256) void tern_write_convb(const float* __restrict__ w,
                                                        const double* __restrict__ st, int total,
                                                        int CIN, unsigned short* __restrict__ out) {
  int i = blockIdx.x * 256 + threadIdx.x;
  if (i >= total) return;
  double delta = 0.7 * st[0] / (double)total;
  double v = (double)w[i];
  float code = v > delta ? 1.f : (v < -delta ? -1.f : 0.f);
  int cin9 = CIN * 9;
  int o = i / cin9, rem = i - o * cin9;
  int ci = rem / 9, tap = rem - ci * 9;
  out[(size_t)o * cin9 + tap * CIN + ci] = f2us(code);
}

// conv1 weights (cin=3) -> bf16 codes padded to 32 ci: [64][k=tap*32+ci]
__global__ __launch_bounds__(256) void tern_write_convb_pad(const float* __restrict__ w,
                                                            const double* __restrict__ st,
                                                            unsigned short* __restrict__ out) {
  int i = blockIdx.x * 256 + threadIdx.x;
  if (i >= 64 * 288) return;
  int o = i / 288, rem = i - o * 288;
  int tap = rem >> 5, ci = rem & 31;
  float code = 0.f;
  if (ci < 3) {
    double delta = 0.7 * st[0] / 1728.0;
    double v = (double)w[(o * 3 + ci) * 9 + tap];
    code = v > delta ? 1.f : (v < -delta ? -1.f : 0.f);
  }
  out[i] = f2us(code);
}

// ---------------- BN finalize (alpha-folded; bias cancels exactly) ----------------
__global__ __launch_bounds__(256) void bn_fin_alpha(const double* __restrict__ pS,
                                                    const double* __restrict__ pQ, int P,
                                                    const float* __restrict__ g,
                                                    const float* __restrict__ be, double M,
                                                    const double* __restrict__ st, double nels,
                                                    float* __restrict__ scsh, int C) {
  __shared__ double lds[4];
  const int c = blockIdx.x;
  double s = 0.0, q = 0.0;
  for (int p = threadIdx.x; p < P; p += 256) {
    s += pS[(size_t)c * P + p];
    q += pQ[(size_t)c * P + p];
  }
  s = dbl_block_reduce(s, lds);
  q = dbl_block_reduce(q, lds);
  if (threadIdx.x == 0) {
    double al = tern_alpha_dd(st, nels);
    double mean = s / M;
    double var = q / M - mean * mean;
    double sc = (double)g[c] * al / sqrt(al * al * var + 1e-5);
    scsh[c] = (float)sc;
    scsh[C + c] = (float)((double)be[c] - mean * sc);
  }
}

// ---------------- x NCHW(3ch) -> NHWC padded to 32ch fp32 ----------------
__global__ __launch_bounds__(256) void pad32(const float* __restrict__ x,
                                             float* __restrict__ x32) {
  int i = blockIdx.x * 256 + threadIdx.x;  // 32*16384
  int px = i & 16383, n = i >> 14;
  float v0 = x[((size_t)n * 3 + 0) * 16384 + px];
  float v1 = x[((size_t)n * 3 + 1) * 16384 + px];
  float v2 = x[((size_t)n * 3 + 2) * 16384 + px];
  float4* dst = (float4*)(x32 + (size_t)i * 32);
  dst[0] = make_float4(v0, v1, v2, 0.f);
  float4 z = make_float4(0.f, 0.f, 0.f, 0.f);
#pragma unroll
  for (int j = 1; j < 8; ++j) dst[j] = z;
}

// ---------------- MFMA implicit-GEMM conv body (hi/lo bf16 split) ----------------
template <int CIN, int H, int PH, int NW>
DEV void conv_body(const float* __restrict__ inNHWC, const unsigned short* __restrict__ wT,
                   int wvCout, int n, int x0, int y0, unsigned short* hiT, unsigned short* loT,
                   f32x4 (&acc)[2][PH]) {
  constexpr int W = H;
  constexpr int K = 9 * CIN;
  constexpr int CH = CIN / 32;
  constexpr int NU = (PH + 2) * 18 * 4;
  const int lane = threadIdx.x & 63;
  const int l15 = lane & 15, l4 = lane >> 4;

#pragma unroll
  for (int g = 0; g < 2; ++g)
#pragma unroll
    for (int pt = 0; pt < PH; ++pt) acc[g][pt] = (f32x4){0.f, 0.f, 0.f, 0.f};

#pragma unroll 1
  for (int cc = 0; cc < CH; ++cc) {
    __syncthreads();
    for (int u = threadIdx.x; u < NU; u += NW * 64) {
      int q = u & 3, rem = u >> 2;
      int xx = rem % 18, yy = rem / 18;
      int gy = y0 + yy - 1, gx = x0 + xx - 1;
      us8 hv = (us8)0, lv = (us8)0;
      if ((unsigned)gy < (unsigned)H && (unsigned)gx < (unsigned)W) {
        const float* src = inNHWC + (((size_t)(n * H + gy) * W + gx) * CIN + cc * 32 + q * 8);
        float4 a = *(const float4*)src;
        float4 c = *(const float4*)(src + 4);
        float f[8] = {a.x, a.y, a.z, a.w, c.x, c.y, c.z, c.w};
#pragma unroll
        for (int j = 0; j < 8; ++j) {
          __hip_bfloat16 h = __float2bfloat16(f[j]);
          unsigned short hu;
          __builtin_memcpy(&hu, &h, 2);
          hv[j] = hu;
          lv[j] = f2us(f[j] - __bfloat162float(h));
        }
      }
      int off = (rem << 5) + (q << 3);
      *(us8*)(hiT + off) = hv;
      *(us8*)(loT + off) = lv;
    }
    __syncthreads();

#pragma unroll
    for (int tap = 0; tap < 9; ++tap) {
      const int dy = tap / 3, dx = tap % 3;
      bf16x8 aF[2];
#pragma unroll
      for (int g = 0; g < 2; ++g) {
        int co = wvCout + g * 16 + l15;
        aF[g] = *(const bf16x8*)(wT + (size_t)co * K + tap * CIN + cc * 32 + l4 * 8);
      }
      const int tb = (dy * 18 + dx + l15) * 32 + l4 * 8;
#pragma unroll
      for (int pt = 0; pt < PH; ++pt) {
        int off = tb + pt * (18 * 32);
        bf16x8 bh = *(const bf16x8*)(hiT + off);
        bf16x8 bl = *(const bf16x8*)(loT + off);
        acc[0][pt] = __builtin_amdgcn_mfma_f32_16x16x32_bf16(aF[0], bh, acc[0][pt], 0, 0, 0);
        acc[1][pt] = __builtin_amdgcn_mfma_f32_16x16x32_bf16(aF[1], bh, acc[1][pt], 0, 0, 0);
        acc[0][pt] = __builtin_amdgcn_mfma_f32_16x16x32_bf16(aF[0], bl, acc[0][pt], 0, 0, 0);
        acc[1][pt] = __builtin_amdgcn_mfma_f32_16x16x32_bf16(aF[1], bl, acc[1][pt], 0, 0, 0);
      }
    }
  }
}

// fused fp64 BN partial write (per wave, 16-lane reduce)
template <int PH>
DEV void bn_partials(const f32x4 (&acc)[2][PH], int wvCout, int p, int P,
                     double* __restrict__ pS, double* __restrict__ pQ) {
  const int lane = threadIdx.x & 63;
  const int l15 = lane & 15, l4 = lane >> 4;
#pragma unroll
  for (int g = 0; g < 2; ++g) {
    float sv[4] = {0, 0, 0, 0}, qv[4] = {0, 0, 0, 0};
#pragma unroll
    for (int pt = 0; pt < PH; ++pt)
#pragma unroll
      for (int r = 0; r < 4; ++r) {
        float v = acc[g][pt][r];
        sv[r] += v;
        qv[r] = fmaf(v, v, qv[r]);
      }
#pragma unroll
    for (int r = 0; r < 4; ++r)
#pragma unroll
      for (int m = 1; m < 16; m <<= 1) {
        sv[r] += __shfl_xor(sv[r], m);
        qv[r] += __shfl_xor(qv[r], m);
      }
    if (l15 == 0) {
#pragma unroll
      for (int r = 0; r < 4; ++r) {
        int co = wvCout + g * 16 + l4 * 4 + r;
        pS[(size_t)co * P + p] = (double)sv[r];
        pQ[(size_t)co * P + p] = (double)qv[r];
      }
    }
  }
}

// layers 2-4: z store (NHWC fp32, f32x4 per lane: acc regs = 4 consecutive couts) + partials
template <int CIN, int H, int PH>
__global__ __launch_bounds__(256) void conv_mfma(const float* __restrict__ inNHWC,
                                                 const unsigned short* __restrict__ wT,
                                                 float* __restrict__ z, int COUT,
                                                 double* __restrict__ pS,
                                                 double* __restrict__ pQ, int P) {
  constexpr int W = H;
  constexpr int TX = W / 16;
  __shared__ unsigned short hiT[(PH + 2) * 18 * 32];
  __shared__ unsigned short loT[(PH + 2) * 18 * 32];
  const int bx = blockIdx.x;
  const int tX = bx % TX, tY = bx / TX;
  const int n = blockIdx.z;
  const int wave = threadIdx.x >> 6, lane = threadIdx.x & 63;
  const int l15 = lane & 15, l4 = lane >> 4;
  const int wvCout = blockIdx.y * 128 + wave * 32;
  const int x0 = tX * 16, y0 = tY * PH;
  f32x4 acc[2][PH];
  conv_body<CIN, H, PH, 4>(inNHWC, wT, wvCout, n, x0, y0, hiT, loT, acc);
#pragma unroll
  for (int g = 0; g < 2; ++g) {
    const int co0 = wvCout + g * 16 + l4 * 4;
#pragma unroll
    for (int pt = 0; pt < PH; ++pt) {
      int oy = y0 + pt;
      *(f32x4*)(z + ((size_t)((n * H + oy) * W) + x0 + l15) * COUT + co0) = acc[g][pt];
    }
  }
  bn_partials<PH>(acc, wvCout, n * gridDim.x + bx, P, pS, pQ);
}

// layer 1 pass 1: partials only (z never materialized)
__global__ __launch_bounds__(128) void conv1_mfma_stats(const float* __restrict__ inNHWC,
                                                        const unsigned short* __restrict__ wT,
                                                        double* __restrict__ pS,
                                                        double* __restrict__ pQ) {
  __shared__ unsigned short hiT[10 * 18 * 32];
  __shared__ unsigned short loT[10 * 18 * 32];
  const int bx = blockIdx.x;
  const int tX = bx & 7, tY = bx >> 3;
  const int n = blockIdx.z;
  const int wave = threadIdx.x >> 6;
  const int wvCout = wave * 32;
  f32x4 acc[2][8];
  conv_body<32, 128, 8, 2>(inNHWC, wT, wvCout, n, tX * 16, tY * 8, hiT, loT, acc);
  bn_partials<8>(acc, wvCout, n * gridDim.x + bx, 4096, pS, pQ);
}

// layer 1 pass 2: recompute, BN+relu+2x2 maxpool, write pooled NHWC directly
__global__ __launch_bounds__(128) void conv1_mfma_pool(const float* __restrict__ inNHWC,
                                                       const unsigned short* __restrict__ wT,
                                                       const float* __restrict__ scsh,
                                                       float* __restrict__ outNHWC) {
  __shared__ unsigned short hiT[10 * 18 * 32];
  __shared__ unsigned short loT[10 * 18 * 32];
  const int bx = blockIdx.x;
  const int tX = bx & 7, tY = bx >> 3;
  const int n = blockIdx.z;
  const int wave = threadIdx.x >> 6, lane = threadIdx.x & 63;
  const int l15 = lane & 15, l4 = lane >> 4;
  const int wvCout = wave * 32;
  const int x0 = tX * 16, y0 = tY * 8;
  f32x4 acc[2][8];
  conv_body<32, 128, 8, 2>(inNHWC, wT, wvCout, n, x0, y0, hiT, loT, acc);
#pragma unroll
  for (int g = 0; g < 2; ++g) {
    const int co0 = wvCout + g * 16 + l4 * 4;
#pragma unroll
    for (int pt = 0; pt < 8; pt += 2) {
      float m[4];
#pragma unroll
      for (int r = 0; r < 4; ++r) {
        float sc = scsh[co0 + r], sh = scsh[64 + co0 + r];
        float v0 = fmaxf(fmaf(acc[g][pt][r], sc, sh), 0.f);
        float v1 = fmaxf(fmaf(acc[g][pt + 1][r], sc, sh), 0.f);
        float a = fmaxf(v0, v1);
        m[r] = fmaxf(a, __shfl_xor(a, 1));
      }
      if ((l15 & 1) == 0) {
        int oy = (y0 + pt) >> 1, ox = (x0 + l15) >> 1;
        *(float4*)(outNHWC + ((((size_t)n * 64 + oy) * 64 + ox) << 6) + co0) =
            make_float4(m[0], m[1], m[2], m[3]);
      }
    }
  }
}

// ---------------- fused norm+relu+pool, NHWC z in ----------------
// L2/L3: pooled NHWC out (float4 both sides). i over N*Ho*Wo*(C/4).
__global__ __launch_bounds__(256) void bn_pool_nhwc(const float* __restrict__ z,
                                                    const float* __restrict__ scsh, int C, int H,
                                                    float* __restrict__ out) {
  const int Cq = C >> 2, Ho = H >> 1;
  int i = blockIdx.x * 256 + threadIdx.x;
  int cq = i % Cq, rest = i / Cq;
  int wo = rest % Ho;
  rest /= Ho;
  int ho = rest % Ho, n = rest / Ho;
  float4 sc = *(const float4*)(scsh + 4 * cq);
  float4 sh = *(const float4*)(scsh + C + 4 * cq);
  size_t base = (((size_t)(n * H + 2 * ho) * H) + 2 * wo) * C + 4 * cq;
  const size_t rowS = (size_t)H * C;
  float4 a = *(const float4*)(z + base);
  float4 b = *(const float4*)(z + base + C);
  float4 c = *(const float4*)(z + base + rowS);
  float4 d = *(const float4*)(z + base + rowS + C);
  float4 r;
  r.x = fmaxf(fmaxf(fmaxf(fmaf(a.x, sc.x, sh.x), fmaf(b.x, sc.x, sh.x)),
                    fmaxf(fmaf(c.x, sc.x, sh.x), fmaf(d.x, sc.x, sh.x))), 0.f);
  r.y = fmaxf(fmaxf(fmaxf(fmaf(a.y, sc.y, sh.y), fmaf(b.y, sc.y, sh.y)),
                    fmaxf(fmaf(c.y, sc.y, sh.y), fmaf(d.y, sc.y, sh.y))), 0.f);
  r.z = fmaxf(fmaxf(fmaxf(fmaf(a.z, sc.z, sh.z), fmaf(b.z, sc.z, sh.z)),
                    fmaxf(fmaf(c.z, sc.z, sh.z), fmaf(d.z, sc.z, sh.z))), 0.f);
  r.w = fmaxf(fmaxf(fmaxf(fmaf(a.w, sc.w, sh.w), fmaf(b.w, sc.w, sh.w)),
                    fmaxf(fmaf(c.w, sc.w, sh.w), fmaf(d.w, sc.w, sh.w))), 0.f);
  *(float4*)(out + (((size_t)(n * Ho + ho) * Ho) + wo) * C + 4 * cq) = r;
}

// L4: pooled NCHW out (matches fc1 k-ordering = c*64+ho*8+wo). Scattered 4B writes, 4MB only.
__global__ __launch_bounds__(256) void bn_pool_nchw(const float* __restrict__ z,
                                                    const float* __restrict__ scsh, int C, int H,
                                                    float* __restrict__ out) {
  const int Cq = C >> 2, Ho = H >> 1;
  int i = blockIdx.x * 256 + threadIdx.x;
  int cq = i % Cq, rest = i / Cq;
  int wo = rest % Ho;
  rest /= Ho;
  int ho = rest % Ho, n = rest / Ho;
  float4 sc = *(const float4*)(scsh + 4 * cq);
  float4 sh = *(const float4*)(scsh + C + 4 * cq);
  size_t base = (((size_t)(n * H + 2 * ho) * H) + 2 * wo) * C + 4 * cq;
  const size_t rowS = (size_t)H * C;
  float4 a = *(const float4*)(z + base);
  float4 b = *(const float4*)(z + base + C);
  float4 c = *(const float4*)(z + base + rowS);
  float4 d = *(const float4*)(z + base + rowS + C);
  float r[4];
  r[0] = fmaxf(fmaxf(fmaxf(fmaf(a.x, sc.x, sh.x), fmaf(b.x, sc.x, sh.x)),
                     fmaxf(fmaf(c.x, sc.x, sh.x), fmaf(d.x, sc.x, sh.x))), 0.f);
  r[1] = fmaxf(fmaxf(fmaxf(fmaf(a.y, sc.y, sh.y), fmaf(b.y, sc.y, sh.y)),
                     fmaxf(fmaf(c.y, sc.y, sh.y), fmaf(d.y, sc.y, sh.y))), 0.f);
  r[2] = fmaxf(fmaxf(fmaxf(fmaf(a.z, sc.z, sh.z), fmaf(b.z, sc.z, sh.z)),
                     fmaxf(fmaf(c.z, sc.z, sh.z), fmaf(d.z, sc.z, sh.z))), 0.f);
  r[3] = fmaxf(fmaxf(fmaxf(fmaf(a.w, sc.w, sh.w), fmaf(b.w, sc.w, sh.w)),
                     fmaxf(fmaf(c.w, sc.w, sh.w), fmaf(d.w, sc.w, sh.w))), 0.f);
#pragma unroll
  for (int j = 0; j < 4; ++j)
    out[(((size_t)n * C + 4 * cq + j) * Ho + ho) * Ho + wo] = r[j];
}

// ---------------- pooled4 fp32 -> hi/lo bf16 ----------------
__global__ __launch_bounds__(256) void hilo_split(const float* __restrict__ in,
                                                  unsigned short* __restrict__ hi,
                                                  unsigned short* __restrict__ lo, int n) {
  int i = blockIdx.x * 256 + threadIdx.x;
  if (i >= n) return;
  float f = in[i];
  __hip_bfloat16 h = __float2bfloat16(f);
  unsigned short hu;
  __builtin_memcpy(&hu, &h, 2);
  hi[i] = hu;
  lo[i] = f2us(f - __bfloat162float(h));
}

// ---------------- FC1 MFMA GEMM: A = int8 codes converted in-register ----------------
DEV bf16x8 i8_to_bf16x8(i8x8 v) {
  us8 u;
#pragma unroll
  for (int j = 0; j < 8; ++j) {
    int c = v[j];
    u[j] = (unsigned short)(c == 0 ? 0 : (c > 0 ? 0x3F80 : 0xBF80));
  }
  bf16x8 r;
  __builtin_memcpy(&r, &u, 16);
  return r;
}

// grid (8 o-blocks, 32 k-slices) = 256 blocks; wave = 32 outs; partial fp32 [s][o][n]
__global__ __launch_bounds__(256) void fc1_mfma(const int8_t* __restrict__ c1,
                                                const unsigned short* __restrict__ aHi,
                                                const unsigned short* __restrict__ aLo,
                                                float* __restrict__ partial) {
  const int w = threadIdx.x >> 6, lane = threadIdx.x & 63;
  const int l15 = lane & 15, l4 = lane >> 4;
  const int o0 = blockIdx.x * 128 + w * 32;
  const int s = blockIdx.y;
  const int kbase = s * 1024 + l4 * 8;
  f32x4 acc[2][2];
#pragma unroll
  for (int g = 0; g < 2; ++g)
#pragma unroll
    for (int t = 0; t < 2; ++t) acc[g][t] = (f32x4){0.f, 0.f, 0.f, 0.f};
#pragma unroll 2
  for (int kc = 0; kc < 1024; kc += 32) {
    bf16x8 a0 = i8_to_bf16x8(*(const i8x8*)(c1 + (size_t)(o0 + l15) * 32768 + kbase + kc));
    bf16x8 a1 = i8_to_bf16x8(*(const i8x8*)(c1 + (size_t)(o0 + 16 + l15) * 32768 + kbase + kc));
    bf16x8 bh0 = *(const bf16x8*)(aHi + (size_t)l15 * 32768 + kbase + kc);
    bf16x8 bl0 = *(const bf16x8*)(aLo + (size_t)l15 * 32768 + kbase + kc);
    bf16x8 bh1 = *(const bf16x8*)(aHi + (size_t)(16 + l15) * 32768 + kbase + kc);
    bf16x8 bl1 = *(const bf16x8*)(aLo + (size_t)(16 + l15) * 32768 + kbase + kc);
    acc[0][0] = __builtin_amdgcn_mfma_f32_16x16x32_bf16(a0, bh0, acc[0][0], 0, 0, 0);
    acc[0][0] = __builtin_amdgcn_mfma_f32_16x16x32_bf16(a0, bl0, acc[0][0], 0, 0, 0);
    acc[1][0] = __builtin_amdgcn_mfma_f32_16x16x32_bf16(a1, bh0, acc[1][0], 0, 0, 0);
    acc[1][0] = __builtin_amdgcn_mfma_f32_16x16x32_bf16(a1, bl0, acc[1][0], 0, 0, 0);
    acc[0][1] = __builtin_amdgcn_mfma_f32_16x16x32_bf16(a0, bh1, acc[0][1], 0, 0, 0);
    acc[0][1] = __builtin_amdgcn_mfma_f32_16x16x32_bf16(a0, bl1, acc[0][1], 0, 0, 0);
    acc[1][1] = __builtin_amdgcn_mfma_f32_16x16x32_bf16(a1, bh1, acc[1][1], 0, 0, 0);
    acc[1][1] = __builtin_amdgcn_mfma_f32_16x16x32_bf16(a1, bl1, acc[1][1], 0, 0, 0);
  }
#pragma unroll
  for (int g = 0; g < 2; ++g)
#pragma unroll
    for (int t = 0; t < 2; ++t)
#pragma unroll
      for (int r = 0; r < 4; ++r) {
        int o = o0 + g * 16 + l4 * 4 + r;
        int n = t * 16 + l15;
        partial[((size_t)s * 1024 + o) * 32 + n] = acc[g][t][r];
      }
}

__global__ __launch_bounds__(256) void fc1_fin(const float* __restrict__ partial,
                                               const double* __restrict__ st,
                                               const float* __restrict__ fb,
                                               float* __restrict__ fc1T) {
  int i = blockIdx.x * 256 + threadIdx.x;  // 32768
  int o = i >> 5;
  float s = 0.f;
#pragma unroll
  for (int t = 0; t < 32; ++t) s += partial[(size_t)t * 32768 + i];
  float alpha = tern_alpha_d(st, 33554432.0);
  fc1T[i] = fmaxf(fmaf(s, alpha, fb[o]), 0.f);
}

// ---------------- FC2 (row-parallel; tiny) ----------------
__global__ __launch_bounds__(256) void fc2_kernel(const float* __restrict__ xT,
                                                  const int8_t* __restrict__ codes,
                                                  const double* __restrict__ st,
                                                  const float* __restrict__ fb,
                                                  float* __restrict__ out) {
  const int o = blockIdx.x;
  float acc[32];
#pragma unroll
  for (int j = 0; j < 32; ++j) acc[j] = 0.f;
  const int8_t* crow = codes + (size_t)o * 1024;
  for (int k = threadIdx.x; k < 1024; k += 256) {
    int cv = crow[k];
    if (cv != 0) {
      float c = (float)cv;
      const float4* pv = (const float4*)(xT + ((size_t)k << 5));
#pragma unroll
      for (int j = 0; j < 8; ++j) {
        float4 v = pv[j];
        acc[4 * j + 0] = fmaf(c, v.x, acc[4 * j + 0]);
        acc[4 * j + 1] = fmaf(c, v.y, acc[4 * j + 1]);
        acc[4 * j + 2] = fmaf(c, v.z, acc[4 * j + 2]);
        acc[4 * j + 3] = fmaf(c, v.w, acc[4 * j + 3]);
      }
    }
  }
#pragma unroll
  for (int j = 0; j < 32; ++j) {
#pragma unroll
    for (int off = 32; off > 0; off >>= 1) acc[j] += __shfl_down(acc[j], off);
  }
  __shared__ float red[4][32];
  int lane = threadIdx.x & 63, wv = threadIdx.x >> 6;
  if (lane == 0) {
#pragma unroll
    for (int j = 0; j < 32; ++j) red[wv][j] = acc[j];
  }
  __syncthreads();
  if (threadIdx.x < 32) {
    int n = threadIdx.x;
    float alpha = tern_alpha_d(st, 1024000.0);
    out[(size_t)n * 1000 + o] = (red[0][n] + red[1][n] + red[2][n] + red[3][n]) * alpha + fb[o];
  }
}

// ---------------- host ----------------
extern "C" void kernel_launch(void* const* d_in, const int* in_sizes, int n_in, void* d_out,
                              int out_size, void* d_ws, size_t ws_size, hipStream_t stream) {
  const float* x = (const float*)d_in[0];
  const float* w1 = (const float*)d_in[1];
  const float* g1 = (const float*)d_in[3];
  const float* be1 = (const float*)d_in[4];
  const float* w2 = (const float*)d_in[5];
  const float* g2 = (const float*)d_in[7];
  const float* be2 = (const float*)d_in[8];
  const float* w3 = (const float*)d_in[9];
  const float* g3 = (const float*)d_in[11];
  const float* be3 = (const float*)d_in[12];
  const float* w4 = (const float*)d_in[13];
  const float* g4 = (const float*)d_in[15];
  const float* be4 = (const float*)d_in[16];
  const float* fw1 = (const float*)d_in[17];
  const float* fb1 = (const float*)d_in[18];
  const float* fw2 = (const float*)d_in[19];
  const float* fb2 = (const float*)d_in[20];
  // b1..b4 cancel exactly under training-mode BN (alpha-folded finalize).
  (void)in_sizes; (void)n_in; (void)out_size; (void)ws_size;

  char* ws = (char*)d_ws;
  size_t off = 0;
  auto alloc = [&](size_t bytes) {
    size_t o = off;
    off += (bytes + 255) & ~(size_t)255;
    return o;
  };
  unsigned short* wb1 = (unsigned short*)(ws + alloc((size_t)18432 * 2));    // [64][288]
  unsigned short* wb2 = (unsigned short*)(ws + alloc((size_t)73728 * 2));    // [128][576]
  unsigned short* wb3 = (unsigned short*)(ws + alloc((size_t)294912 * 2));   // [256][1152]
  unsigned short* wb4 = (unsigned short*)(ws + alloc((size_t)1179648 * 2));  // [512][2304]
  int8_t* c1 = (int8_t*)(ws + alloc((size_t)33554432));  // fc1 int8 codes [1024][32768]
  int8_t* c2 = (int8_t*)(ws + alloc((size_t)1024000));
  double* dst = (double*)(ws + alloc((size_t)32 * 8));
  float* scsh = (float*)(ws + alloc((size_t)4096 * 4));
  double* pS = (double*)(ws + alloc((size_t)262144 * 8));
  double* pQ = (double*)(ws + alloc((size_t)262144 * 8));
  float* bufY = (float*)(ws + alloc((size_t)16777216 * 4));  // 67MB: x32pad / z (NHWC)
  float* bufA = (float*)(ws + alloc((size_t)8388608 * 4));   // 33.5MB: pooled acts
  unsigned short* actHi = (unsigned short*)(ws + alloc((size_t)1048576 * 2));
  unsigned short* actLo = (unsigned short*)(ws + alloc((size_t)1048576 * 2));
  float* fc1part = (float*)(ws + alloc((size_t)1048576 * 4));  // [32][1024][32]
  float* fc1T = (float*)(ws + alloc((size_t)32768 * 4));       // [1024][32]
  float* x32 = bufY;              // NHWC-32 input, dead after conv1
  float* bufA2 = bufA + 4194304;  // ping-pong half
  // total ~152 MB (163 MB proven mapped in R1)

  hipMemsetAsync(dst, 0, 32 * 8, stream);

  // ternarize stats: one abs launch + one fused masked+code launch for all 6 tensors
  TDescs ta;
  ta.d[0] = {w1, 1728};
  ta.d[1] = {w2, 73728};
  ta.d[2] = {w3, 294912};
  ta.d[3] = {w4, 1179648};
  ta.d[4] = {fw1, 33554432};
  ta.d[5] = {fw2, 1024000};
  tern_abs_all<<<dim3(2048, 6), 256, 0, stream>>>(ta, dst);
  MDescs tm;
  tm.d[0] = {w1, nullptr, 1728};
  tm.d[1] = {w2, nullptr, 73728};
  tm.d[2] = {w3, nullptr, 294912};
  tm.d[3] = {w4, nullptr, 1179648};
  tm.d[4] = {fw1, c1, 33554432};
  tm.d[5] = {fw2, c2, 1024000};
  tern_masked_code_all<<<dim3(2048, 6), 256, 0, stream>>>(tm, dst);
  tern_write_convb_pad<<<72, 256, 0, stream>>>(w1, dst + 0, wb1);
  tern_write_convb<<<288, 256, 0, stream>>>(w2, dst + 4, 73728, 64, wb2);
  tern_write_convb<<<1152, 256, 0, stream>>>(w3, dst + 8, 294912, 128, wb3);
  tern_write_convb<<<4608, 256, 0, stream>>>(w4, dst + 12, 1179648, 256, wb4);

  float* ss1 = scsh;
  float* ss2 = scsh + 128;
  float* ss3 = scsh + 512;
  float* ss4 = scsh + 1024;

  // Layer 1 via MFMA, two-pass recompute; pooled1 written directly as NHWC.
  pad32<<<2048, 256, 0, stream>>>(x, x32);
  conv1_mfma_stats<<<dim3(128, 1, 32), 128, 0, stream>>>(x32, wb1, pS, pQ);
  bn_fin_alpha<<<64, 256, 0, stream>>>(pS, pQ, 4096, g1, be1, 524288.0, dst + 0, 1728.0, ss1,
                                       64);
  conv1_mfma_pool<<<dim3(128, 1, 32), 128, 0, stream>>>(x32, wb1, ss1, bufA);

  // Layer 2: 64->128 @64x64; z NHWC -> bufY; pooled NHWC -> bufA2
  conv_mfma<64, 64, 8><<<dim3(32, 1, 32), 256, 0, stream>>>(bufA, wb2, bufY, 128, pS, pQ, 1024);
  bn_fin_alpha<<<128, 256, 0, stream>>>(pS, pQ, 1024, g2, be2, 131072.0, dst + 4, 73728.0, ss2,
                                        128);
  bn_pool_nhwc<<<4096, 256, 0, stream>>>(bufY, ss2, 128, 64, bufA2);

  // Layer 3: 128->256 @32x32; pooled NHWC -> bufA
  conv_mfma<128, 32, 4><<<dim3(16, 2, 32), 256, 0, stream>>>(bufA2, wb3, bufY, 256, pS, pQ, 512);
  bn_fin_alpha<<<256, 256, 0, stream>>>(pS, pQ, 512, g3, be3, 32768.0, dst + 8, 294912.0, ss3,
                                        256);
  bn_pool_nhwc<<<2048, 256, 0, stream>>>(bufY, ss3, 256, 32, bufA);

  // Layer 4: 256->512 @16x16; pooled NCHW flat [32][32768] -> bufA2 (matches c1 k-order)
  conv_mfma<256, 16, 2><<<dim3(8, 4, 32), 256, 0, stream>>>(bufA, wb4, bufY, 512, pS, pQ, 256);
  bn_fin_alpha<<<512, 256, 0, stream>>>(pS, pQ, 256, g4, be4, 8192.0, dst + 12, 1179648.0, ss4,
                                        512);
  bn_pool_nchw<<<1024, 256, 0, stream>>>(bufY, ss4, 512, 16, bufA2);
  hilo_split<<<4096, 256, 0, stream>>>(bufA2, actHi, actLo, 1048576);

  // FC1 (int8 codes -> in-register bf16), 256 blocks; then finalize + FC2
  fc1_mfma<<<dim3(8, 32), 256, 0, stream>>>(c1, actHi, actLo, fc1part);
  fc1_fin<<<128, 256, 0, stream>>>(fc1part, dst + 16, fb1, fc1T);
  fc2_kernel<<<1000, 256, 0, stream>>>(fc1T, c2, dst + 20, fb2, (float*)d_out);
}